// Round 6
// baseline (522.826 us; speedup 1.0000x reference)
//
#include <hip/hip_runtime.h>
#include <hip/hip_bf16.h>

typedef __attribute__((ext_vector_type(8))) short bf16x8;
typedef __attribute__((ext_vector_type(4))) float f32x4;

#define NROWS 262144
#define MBLK  64
#define NBLKS (NROWS / MBLK)   /* 4096 */

// ---------------------------------------------------------------------------
// Weight prep: MFMA B-fragment-layout bf16 hi/lo copies,
// Wbig[gate][n=0..127][k=0..255] (k<128 -> W, else U).
// ---------------------------------------------------------------------------
__global__ void prep_weights(
    const float* __restrict__ Wi, const float* __restrict__ Ui,
    const float* __restrict__ Wf, const float* __restrict__ Uf,
    const float* __restrict__ Wo, const float* __restrict__ Uo,
    const float* __restrict__ Wz, const float* __restrict__ Uz,
    ushort* __restrict__ hi, ushort* __restrict__ lo)
{
    int idx = blockIdx.x * 256 + threadIdx.x;   // 0..131071
    int j    = idx & 7;
    int lane = (idx >> 3) & 63;
    int kk   = (idx >> 9) & 7;
    int ni   = (idx >> 12) & 7;
    int g    = idx >> 15;
    int n = ni * 16 + (lane & 15);
    int k = kk * 32 + (lane >> 4) * 8 + j;
    const float* W; const float* U;
    if (g == 0)      { W = Wi; U = Ui; }
    else if (g == 1) { W = Wf; U = Uf; }
    else if (g == 2) { W = Wo; U = Uo; }
    else             { W = Wz; U = Uz; }
    float w = (k < 128) ? W[n * 128 + k] : U[n * 128 + (k - 128)];
    __hip_bfloat16 hb = __float2bfloat16(w);
    float r = w - __bfloat162float(hb);
    __hip_bfloat16 lb = __float2bfloat16(r);
    hi[idx] = *reinterpret_cast<ushort*>(&hb);
    lo[idx] = *reinterpret_cast<ushort*>(&lb);
}

// ---------------------------------------------------------------------------
// Main fused kernel. 4096 blocks x 1 tile; block = 512 thr = 8 waves.
// LDS = 64 KB total (A-tile hi/lo 32+32 KB; reused as pre[32][512] fp32 in a
// 2-chunk epilogue) -> 2 blocks/CU co-resident; block B's stage/gating
// overlaps block A's K-loop. launch_bounds(512,4) caps VGPR at 128.
// ---------------------------------------------------------------------------
__global__ __launch_bounds__(512, 4) void slstm_main(
    const float* __restrict__ x,     const float* __restrict__ hprev,
    const float* __restrict__ cprev, const float* __restrict__ nprev,
    const float* __restrict__ bi,    const float* __restrict__ bfg,
    const float* __restrict__ bo,    const float* __restrict__ bz,
    const ushort* __restrict__ whi,  const ushort* __restrict__ wlo,
    float* __restrict__ out)
{
    __shared__ float pre[32 * 512];               // 64 KB
    char*   AhiB = reinterpret_cast<char*>(pre);  // first 32 KB: bf16-hi A
    char*   AloB = AhiB + 64 * 256 * 2;           // next 32 KB: bf16-lo A

    const int tid  = threadIdx.x;
    const int row0 = blockIdx.x * MBLK;

    // ---- stage A: fp32 loads, split to bf16 hi+lo, swizzled LDS ----
    #pragma unroll
    for (int i = 0; i < 4; ++i) {
        int f4  = tid + i * 512;
        int row = f4 >> 5;
        int c4  = f4 & 31;
        f32x4 vx = reinterpret_cast<const f32x4*>(x)[(size_t)(row0 + row) * 32 + c4];
        f32x4 vh = reinterpret_cast<const f32x4*>(hprev)[(size_t)(row0 + row) * 32 + c4];
        #pragma unroll
        for (int half = 0; half < 2; ++half) {
            f32x4 v = half ? vh : vx;
            int kbase = half * 128 + 4 * c4;
            int q   = kbase >> 3;
            int sub = (kbase & 7) * 2;
            int byt = row * 512 + ((q ^ (row & 7)) << 4) + sub;
            ushort h4[4], l4v[4];
            #pragma unroll
            for (int e = 0; e < 4; ++e) {
                float ve = v[e];
                __hip_bfloat16 hb = __float2bfloat16(ve);
                float r = ve - __bfloat162float(hb);
                __hip_bfloat16 lb = __float2bfloat16(r);
                h4[e]  = *reinterpret_cast<ushort*>(&hb);
                l4v[e] = *reinterpret_cast<ushort*>(&lb);
            }
            uint2 hp, lp;
            hp.x = (uint)h4[0] | ((uint)h4[1] << 16);
            hp.y = (uint)h4[2] | ((uint)h4[3] << 16);
            lp.x = (uint)l4v[0] | ((uint)l4v[1] << 16);
            lp.y = (uint)l4v[2] | ((uint)l4v[3] << 16);
            *reinterpret_cast<uint2*>(AhiB + byt) = hp;
            *reinterpret_cast<uint2*>(AloB + byt) = lp;
        }
    }
    __syncthreads();   // bar 1

    const int wid  = tid >> 6;
    const int lane = tid & 63;
    const int g    = wid & 3;
    const int ch   = wid >> 2;
    const int l15  = lane & 15;
    const int lg   = lane >> 4;
    const int c    = tid & 127;        // epilogue column (0..127 within gate 0)
    const int r0   = tid >> 7;         // epilogue row phase 0..3

    // ---- hoist c/n loads (32-bit offsets off SGPR-friendly bases);
    //      latency hides under the K-loop ----
    const float* cB = cprev + (size_t)row0 * 128 + c;
    const float* nB = nprev + (size_t)row0 * 128 + c;
    float cpr[16], npr[16];
    #pragma unroll
    for (int it = 0; it < 16; ++it) {
        int off = (r0 + it * 4) * 128;
        cpr[it] = cB[off];
        npr[it] = nB[off];
    }

    // wave-constant B base
    const ushort* whiW = whi + (size_t)(g * 64 + ch * 32) * 512 + lane * 8;
    const ushort* wloW = wlo + (size_t)(g * 64 + ch * 32) * 512 + lane * 8;

    // ---- K-loop: 3-term split-precision MFMA ----
    f32x4 acc[4][4] = {};   // [mi][ni]; wave tile = 64 rows x 64 cols

    #pragma unroll
    for (int kk = 0; kk < 8; ++kk) {
        bf16x8 ah[4], al[4];
        #pragma unroll
        for (int mi = 0; mi < 4; ++mi) {
            int row = mi * 16 + l15;
            int q   = kk * 4 + lg;
            int byt = row * 512 + ((q ^ (row & 7)) << 4);
            ah[mi] = *reinterpret_cast<const bf16x8*>(AhiB + byt);
            al[mi] = *reinterpret_cast<const bf16x8*>(AloB + byt);
        }
        #pragma unroll
        for (int ni = 0; ni < 4; ++ni) {
            int eoff = (ni * 8 + kk) * 512;
            bf16x8 bh = *reinterpret_cast<const bf16x8*>(whiW + eoff);
            bf16x8 bl = *reinterpret_cast<const bf16x8*>(wloW + eoff);
            #pragma unroll
            for (int mi = 0; mi < 4; ++mi)
                acc[mi][ni] = __builtin_amdgcn_mfma_f32_16x16x32_bf16(ah[mi], bh, acc[mi][ni], 0, 0, 0);
            #pragma unroll
            for (int mi = 0; mi < 4; ++mi)
                acc[mi][ni] = __builtin_amdgcn_mfma_f32_16x16x32_bf16(ah[mi], bl, acc[mi][ni], 0, 0, 0);
            #pragma unroll
            for (int mi = 0; mi < 4; ++mi)
                acc[mi][ni] = __builtin_amdgcn_mfma_f32_16x16x32_bf16(al[mi], bh, acc[mi][ni], 0, 0, 0);
        }
    }

    // ---- 2-chunk epilogue: 32 rows per chunk through 64 KB pre ----
    const size_t OUTS = (size_t)NROWS * 128;
    float* outB = out + (size_t)row0 * 128 + c;
    const float bic = bi[c], bfc = bfg[c], boc = bo[c], bzc = bz[c];

    #pragma unroll
    for (int ck = 0; ck < 2; ++ck) {
        __syncthreads();   // ck=0: K-loop LDS reads done; ck=1: chunk0 reads done
        #pragma unroll
        for (int mm = 0; mm < 2; ++mm) {
            int mi = ck * 2 + mm;
            #pragma unroll
            for (int ni = 0; ni < 4; ++ni) {
                int colF = g * 128 + ch * 64 + ni * 16 + l15;
                #pragma unroll
                for (int r = 0; r < 4; ++r) {
                    int rowp = mm * 16 + lg * 4 + r;   // local row 0..31
                    pre[rowp * 512 + (colF ^ ((rowp & 4) << 2))] = acc[mi][ni][r];
                }
            }
        }
        __syncthreads();

        #pragma unroll
        for (int it = 0; it < 8; ++it) {
            int rl = r0 + it * 4;          // local row 0..31
            int rr = ck * 32 + rl;         // row within tile
            int sw = (rl & 4) << 2;
            float pit = pre[rl * 512 + ((      c) ^ sw)] + bic;
            float pft = pre[rl * 512 + ((128 + c) ^ sw)] + bfc;
            float pot = pre[rl * 512 + ((256 + c) ^ sw)] + boc;
            float pzt = pre[rl * 512 + ((384 + c) ^ sw)] + bzc;
            float m   = fmaxf(pft, pit);
            float i_t = __expf(pit - m);
            float f_t = __builtin_amdgcn_rcpf(1.0f + __expf(-pft)) + __expf(pft - m);
            float o_t = __builtin_amdgcn_rcpf(1.0f + __expf(-pot));
            float zc  = fminf(fmaxf(pzt, -15.0f), 15.0f);
            float e2  = __expf(2.0f * zc);
            float z_t = (e2 - 1.0f) * __builtin_amdgcn_rcpf(e2 + 1.0f);
            float cpv = cpr[ck * 8 + it];
            float npv = npr[ck * 8 + it];
            float c_t = f_t * cpv + i_t * z_t;
            float n_t = f_t * npv + i_t;
            float h_t = o_t * c_t * __builtin_amdgcn_rcpf(n_t + 1e-8f);
            int off = rr * 128;
            outB[off]            = h_t;
            outB[OUTS + off]     = c_t;
            outB[2 * OUTS + off] = n_t;
        }
    }
}

extern "C" void kernel_launch(void* const* d_in, const int* in_sizes, int n_in,
                              void* d_out, int out_size, void* d_ws, size_t ws_size,
                              hipStream_t stream) {
    const float* x  = (const float*)d_in[0];
    const float* h  = (const float*)d_in[1];
    const float* cp = (const float*)d_in[2];
    const float* np = (const float*)d_in[3];
    const float* Wi = (const float*)d_in[4];
    const float* Ui = (const float*)d_in[5];
    const float* Wf = (const float*)d_in[6];
    const float* Uf = (const float*)d_in[7];
    const float* Wo = (const float*)d_in[8];
    const float* Uo = (const float*)d_in[9];
    const float* Wz = (const float*)d_in[10];
    const float* Uz = (const float*)d_in[11];
    const float* bi = (const float*)d_in[12];
    const float* bf = (const float*)d_in[13];
    const float* bo = (const float*)d_in[14];
    const float* bz = (const float*)d_in[15];

    ushort* whi = (ushort*)d_ws;                  // 256 KB
    ushort* wlo = whi + 4 * 128 * 256;            // 256 KB

    prep_weights<<<512, 256, 0, stream>>>(Wi, Ui, Wf, Uf, Wo, Uo, Wz, Uz, whi, wlo);
    slstm_main<<<NBLKS, 512, 0, stream>>>(x, h, cp, np, bi, bf, bo, bz, whi, wlo,
                                          (float*)d_out);
}

// Round 7
// 366.906 us; speedup vs baseline: 1.4250x; 1.4250x over previous
//
#include <hip/hip_runtime.h>
#include <hip/hip_bf16.h>

typedef __attribute__((ext_vector_type(8))) short bf16x8;
typedef __attribute__((ext_vector_type(4))) float f32x4;

#define NROWS 262144
#define MBLK  64
#define NBLKS (NROWS / MBLK)   /* 4096 */

// ---------------------------------------------------------------------------
// Weight prep: MFMA B-fragment-layout bf16 hi/lo copies,
// Wbig[gate][n=0..127][k=0..255] (k<128 -> W, else U).
// ---------------------------------------------------------------------------
__global__ void prep_weights(
    const float* __restrict__ Wi, const float* __restrict__ Ui,
    const float* __restrict__ Wf, const float* __restrict__ Uf,
    const float* __restrict__ Wo, const float* __restrict__ Uo,
    const float* __restrict__ Wz, const float* __restrict__ Uz,
    ushort* __restrict__ hi, ushort* __restrict__ lo)
{
    int idx = blockIdx.x * 256 + threadIdx.x;   // 0..131071
    int j    = idx & 7;
    int lane = (idx >> 3) & 63;
    int kk   = (idx >> 9) & 7;
    int ni   = (idx >> 12) & 7;
    int g    = idx >> 15;
    int n = ni * 16 + (lane & 15);
    int k = kk * 32 + (lane >> 4) * 8 + j;
    const float* W; const float* U;
    if (g == 0)      { W = Wi; U = Ui; }
    else if (g == 1) { W = Wf; U = Uf; }
    else if (g == 2) { W = Wo; U = Uo; }
    else             { W = Wz; U = Uz; }
    float w = (k < 128) ? W[n * 128 + k] : U[n * 128 + (k - 128)];
    __hip_bfloat16 hb = __float2bfloat16(w);
    float r = w - __bfloat162float(hb);
    __hip_bfloat16 lb = __float2bfloat16(r);
    hi[idx] = *reinterpret_cast<ushort*>(&hb);
    lo[idx] = *reinterpret_cast<ushort*>(&lb);
}

// ---------------------------------------------------------------------------
// Main fused kernel. 4096 blocks; block = 512 thr = 8 waves; MBLK=64.
// LDS 64 KB -> 2 blocks/CU. Unified-reg budget: acc=64 AGPR + 64 VGPR cap
// from launch_bounds(512,4). To avoid the R4/R6 scratch spills:
//   - stage loop is unroll(1): only 2 f32x4 loads live at a time
//   - no c/n prefetch across the K-loop: JIT loads per epilogue chunk,
//     issued before the chunk barrier so latency hides under it
// ---------------------------------------------------------------------------
__global__ __launch_bounds__(512, 4) void slstm_main(
    const float* __restrict__ x,     const float* __restrict__ hprev,
    const float* __restrict__ cprev, const float* __restrict__ nprev,
    const float* __restrict__ bi,    const float* __restrict__ bfg,
    const float* __restrict__ bo,    const float* __restrict__ bz,
    const ushort* __restrict__ whi,  const ushort* __restrict__ wlo,
    float* __restrict__ out)
{
    __shared__ float pre[32 * 512];               // 64 KB
    char*   AhiB = reinterpret_cast<char*>(pre);  // first 32 KB: bf16-hi A
    char*   AloB = AhiB + 64 * 256 * 2;           // next 32 KB: bf16-lo A

    const int tid  = threadIdx.x;
    const int row0 = blockIdx.x * MBLK;

    // ---- stage A: fp32 loads, split to bf16 hi+lo, swizzled LDS ----
    // unroll(1): keep only one iteration's loads in flight (reg budget)
    #pragma unroll 1
    for (int i = 0; i < 4; ++i) {
        int f4  = tid + i * 512;
        int row = f4 >> 5;
        int c4  = f4 & 31;
        f32x4 vx = reinterpret_cast<const f32x4*>(x)[(size_t)(row0 + row) * 32 + c4];
        f32x4 vh = reinterpret_cast<const f32x4*>(hprev)[(size_t)(row0 + row) * 32 + c4];
        #pragma unroll
        for (int half = 0; half < 2; ++half) {
            f32x4 v = half ? vh : vx;
            int kbase = half * 128 + 4 * c4;
            int q   = kbase >> 3;
            int sub = (kbase & 7) * 2;
            int byt = row * 512 + ((q ^ (row & 7)) << 4) + sub;
            ushort h4[4], l4v[4];
            #pragma unroll
            for (int e = 0; e < 4; ++e) {
                float ve = v[e];
                __hip_bfloat16 hb = __float2bfloat16(ve);
                float r = ve - __bfloat162float(hb);
                __hip_bfloat16 lb = __float2bfloat16(r);
                h4[e]  = *reinterpret_cast<ushort*>(&hb);
                l4v[e] = *reinterpret_cast<ushort*>(&lb);
            }
            uint2 hp, lp;
            hp.x = (uint)h4[0] | ((uint)h4[1] << 16);
            hp.y = (uint)h4[2] | ((uint)h4[3] << 16);
            lp.x = (uint)l4v[0] | ((uint)l4v[1] << 16);
            lp.y = (uint)l4v[2] | ((uint)l4v[3] << 16);
            *reinterpret_cast<uint2*>(AhiB + byt) = hp;
            *reinterpret_cast<uint2*>(AloB + byt) = lp;
        }
    }
    __syncthreads();   // bar 1

    const int wid  = tid >> 6;
    const int lane = tid & 63;
    const int g    = wid & 3;
    const int ch   = wid >> 2;
    const int l15  = lane & 15;
    const int lg   = lane >> 4;
    const int c    = tid & 127;        // epilogue column
    const int r0   = tid >> 7;         // epilogue row phase 0..3

    // wave-constant B base
    const ushort* whiW = whi + (size_t)(g * 64 + ch * 32) * 512 + lane * 8;
    const ushort* wloW = wlo + (size_t)(g * 64 + ch * 32) * 512 + lane * 8;

    // ---- K-loop: 3-term split-precision MFMA ----
    f32x4 acc[4][4] = {};   // [mi][ni]; wave tile = 64 rows x 64 cols

    #pragma unroll
    for (int kk = 0; kk < 8; ++kk) {
        bf16x8 ah[4], al[4];
        #pragma unroll
        for (int mi = 0; mi < 4; ++mi) {
            int row = mi * 16 + l15;
            int q   = kk * 4 + lg;
            int byt = row * 512 + ((q ^ (row & 7)) << 4);
            ah[mi] = *reinterpret_cast<const bf16x8*>(AhiB + byt);
            al[mi] = *reinterpret_cast<const bf16x8*>(AloB + byt);
        }
        #pragma unroll
        for (int ni = 0; ni < 4; ++ni) {
            int eoff = (ni * 8 + kk) * 512;
            bf16x8 bh = *reinterpret_cast<const bf16x8*>(whiW + eoff);
            bf16x8 bl = *reinterpret_cast<const bf16x8*>(wloW + eoff);
            #pragma unroll
            for (int mi = 0; mi < 4; ++mi)
                acc[mi][ni] = __builtin_amdgcn_mfma_f32_16x16x32_bf16(ah[mi], bh, acc[mi][ni], 0, 0, 0);
            #pragma unroll
            for (int mi = 0; mi < 4; ++mi)
                acc[mi][ni] = __builtin_amdgcn_mfma_f32_16x16x32_bf16(ah[mi], bl, acc[mi][ni], 0, 0, 0);
            #pragma unroll
            for (int mi = 0; mi < 4; ++mi)
                acc[mi][ni] = __builtin_amdgcn_mfma_f32_16x16x32_bf16(al[mi], bh, acc[mi][ni], 0, 0, 0);
        }
    }

    // ---- 2-chunk epilogue: 32 rows per chunk through 64 KB pre ----
    const size_t OUTS = (size_t)NROWS * 128;
    const float* cB = cprev + (size_t)row0 * 128 + c;
    const float* nB = nprev + (size_t)row0 * 128 + c;
    float* outB = out + (size_t)row0 * 128 + c;
    const float bic = bi[c], bfc = bfg[c], boc = bo[c], bzc = bz[c];

    #pragma unroll
    for (int ck = 0; ck < 2; ++ck) {
        __syncthreads();   // ck=0: K-loop LDS reads done; ck=1: chunk0 reads done
        #pragma unroll
        for (int mm = 0; mm < 2; ++mm) {
            int mi = ck * 2 + mm;
            #pragma unroll
            for (int ni = 0; ni < 4; ++ni) {
                int colF = g * 128 + ch * 64 + ni * 16 + l15;
                #pragma unroll
                for (int r = 0; r < 4; ++r) {
                    int rowp = mm * 16 + lg * 4 + r;   // local row 0..31
                    pre[rowp * 512 + (colF ^ ((rowp & 4) << 2))] = acc[mi][ni][r];
                }
            }
        }
        // JIT c/n loads for this chunk: issued before the barrier so the
        // ~600cy latency hides under barrier + pre reads
        float cpv[8], npv[8];
        #pragma unroll
        for (int it = 0; it < 8; ++it) {
            int off = (ck * 32 + r0 + it * 4) * 128;
            cpv[it] = cB[off];
            npv[it] = nB[off];
        }
        __syncthreads();

        #pragma unroll
        for (int it = 0; it < 8; ++it) {
            int rl = r0 + it * 4;          // local row 0..31
            int rr = ck * 32 + rl;         // row within tile
            int sw = (rl & 4) << 2;
            float pit = pre[rl * 512 + ((      c) ^ sw)] + bic;
            float pft = pre[rl * 512 + ((128 + c) ^ sw)] + bfc;
            float pot = pre[rl * 512 + ((256 + c) ^ sw)] + boc;
            float pzt = pre[rl * 512 + ((384 + c) ^ sw)] + bzc;
            float m   = fmaxf(pft, pit);
            float i_t = __expf(pit - m);
            float f_t = __builtin_amdgcn_rcpf(1.0f + __expf(-pft)) + __expf(pft - m);
            float o_t = __builtin_amdgcn_rcpf(1.0f + __expf(-pot));
            float zc  = fminf(fmaxf(pzt, -15.0f), 15.0f);
            float e2  = __expf(2.0f * zc);
            float z_t = (e2 - 1.0f) * __builtin_amdgcn_rcpf(e2 + 1.0f);
            float c_t = f_t * cpv[it] + i_t * z_t;
            float n_t = f_t * npv[it] + i_t;
            float h_t = o_t * c_t * __builtin_amdgcn_rcpf(n_t + 1e-8f);
            int off = rr * 128;
            outB[off]            = h_t;
            outB[OUTS + off]     = c_t;
            outB[2 * OUTS + off] = n_t;
        }
    }
}

extern "C" void kernel_launch(void* const* d_in, const int* in_sizes, int n_in,
                              void* d_out, int out_size, void* d_ws, size_t ws_size,
                              hipStream_t stream) {
    const float* x  = (const float*)d_in[0];
    const float* h  = (const float*)d_in[1];
    const float* cp = (const float*)d_in[2];
    const float* np = (const float*)d_in[3];
    const float* Wi = (const float*)d_in[4];
    const float* Ui = (const float*)d_in[5];
    const float* Wf = (const float*)d_in[6];
    const float* Uf = (const float*)d_in[7];
    const float* Wo = (const float*)d_in[8];
    const float* Uo = (const float*)d_in[9];
    const float* Wz = (const float*)d_in[10];
    const float* Uz = (const float*)d_in[11];
    const float* bi = (const float*)d_in[12];
    const float* bf = (const float*)d_in[13];
    const float* bo = (const float*)d_in[14];
    const float* bz = (const float*)d_in[15];

    ushort* whi = (ushort*)d_ws;                  // 256 KB
    ushort* wlo = whi + 4 * 128 * 256;            // 256 KB

    prep_weights<<<512, 256, 0, stream>>>(Wi, Ui, Wf, Uf, Wo, Uo, Wz, Uz, whi, wlo);
    slstm_main<<<NBLKS, 512, 0, stream>>>(x, h, cp, np, bi, bf, bo, bz, whi, wlo,
                                          (float*)d_out);
}

// Round 8
// 332.333 us; speedup vs baseline: 1.5732x; 1.1040x over previous
//
#include <hip/hip_runtime.h>
#include <hip/hip_bf16.h>

typedef __attribute__((ext_vector_type(8))) short bf16x8;
typedef __attribute__((ext_vector_type(4))) float f32x4;

#define NROWS 262144
#define MBLK  32
#define NBLKS (NROWS / MBLK)   /* 8192 */

// ---------------------------------------------------------------------------
// Weight prep: MFMA B-fragment-layout bf16 hi/lo copies,
// Wbig[gate][n=0..127][k=0..255] (k<128 -> W, else U).
// ---------------------------------------------------------------------------
__global__ void prep_weights(
    const float* __restrict__ Wi, const float* __restrict__ Ui,
    const float* __restrict__ Wf, const float* __restrict__ Uf,
    const float* __restrict__ Wo, const float* __restrict__ Uo,
    const float* __restrict__ Wz, const float* __restrict__ Uz,
    ushort* __restrict__ hi, ushort* __restrict__ lo)
{
    int idx = blockIdx.x * 256 + threadIdx.x;   // 0..131071
    int j    = idx & 7;
    int lane = (idx >> 3) & 63;
    int kk   = (idx >> 9) & 7;
    int ni   = (idx >> 12) & 7;
    int g    = idx >> 15;
    int n = ni * 16 + (lane & 15);
    int k = kk * 32 + (lane >> 4) * 8 + j;
    const float* W; const float* U;
    if (g == 0)      { W = Wi; U = Ui; }
    else if (g == 1) { W = Wf; U = Uf; }
    else if (g == 2) { W = Wo; U = Uo; }
    else             { W = Wz; U = Uz; }
    float w = (k < 128) ? W[n * 128 + k] : U[n * 128 + (k - 128)];
    __hip_bfloat16 hb = __float2bfloat16(w);
    float r = w - __bfloat162float(hb);
    __hip_bfloat16 lb = __float2bfloat16(r);
    hi[idx] = *reinterpret_cast<ushort*>(&hb);
    lo[idx] = *reinterpret_cast<ushort*>(&lb);
}

// ---------------------------------------------------------------------------
// Main fused kernel. 8192 blocks; block = 512 thr = 8 waves; MBLK=32.
// Wave tile = 32 rows x 64 cols -> acc[2][4] = 32 regs/thread, leaving
// ~96 arch VGPRs under the launch_bounds(512,4) 128-reg unified cap:
// 2 blocks/CU co-resident WITHOUT the R6/R7 scratch spills.
// LDS 64 KB: A-tile hi/lo in first 32 KB; whole 64 KB reused as
// pre[32][512] fp32 for a single-chunk epilogue (3 barriers total).
// ---------------------------------------------------------------------------
__global__ __launch_bounds__(512, 4) void slstm_main(
    const float* __restrict__ x,     const float* __restrict__ hprev,
    const float* __restrict__ cprev, const float* __restrict__ nprev,
    const float* __restrict__ bi,    const float* __restrict__ bfg,
    const float* __restrict__ bo,    const float* __restrict__ bz,
    const ushort* __restrict__ whi,  const ushort* __restrict__ wlo,
    float* __restrict__ out)
{
    __shared__ float pre[32 * 512];               // 64 KB
    char*   AhiB = reinterpret_cast<char*>(pre);  // first 16 KB: bf16-hi A
    char*   AloB = AhiB + 32 * 256 * 2;           // next 16 KB: bf16-lo A

    const int tid  = threadIdx.x;
    const int row0 = blockIdx.x * MBLK;

    // ---- stage A: fp32 loads, split to bf16 hi+lo, swizzled LDS ----
    #pragma unroll 1
    for (int i = 0; i < 2; ++i) {
        int f4  = tid + i * 512;          // 0..1023
        int row = f4 >> 5;                // 0..31
        int c4  = f4 & 31;
        f32x4 vx = reinterpret_cast<const f32x4*>(x)[(size_t)(row0 + row) * 32 + c4];
        f32x4 vh = reinterpret_cast<const f32x4*>(hprev)[(size_t)(row0 + row) * 32 + c4];
        #pragma unroll
        for (int half = 0; half < 2; ++half) {
            f32x4 v = half ? vh : vx;
            int kbase = half * 128 + 4 * c4;
            int q   = kbase >> 3;
            int sub = (kbase & 7) * 2;
            int byt = row * 512 + ((q ^ (row & 7)) << 4) + sub;
            ushort h4[4], l4v[4];
            #pragma unroll
            for (int e = 0; e < 4; ++e) {
                float ve = v[e];
                __hip_bfloat16 hb = __float2bfloat16(ve);
                float r = ve - __bfloat162float(hb);
                __hip_bfloat16 lb = __float2bfloat16(r);
                h4[e]  = *reinterpret_cast<ushort*>(&hb);
                l4v[e] = *reinterpret_cast<ushort*>(&lb);
            }
            uint2 hp, lp;
            hp.x = (uint)h4[0] | ((uint)h4[1] << 16);
            hp.y = (uint)h4[2] | ((uint)h4[3] << 16);
            lp.x = (uint)l4v[0] | ((uint)l4v[1] << 16);
            lp.y = (uint)l4v[2] | ((uint)l4v[3] << 16);
            *reinterpret_cast<uint2*>(AhiB + byt) = hp;
            *reinterpret_cast<uint2*>(AloB + byt) = lp;
        }
    }
    __syncthreads();   // bar 1

    const int wid  = tid >> 6;
    const int lane = tid & 63;
    const int g    = wid & 3;
    const int ch   = wid >> 2;
    const int l15  = lane & 15;
    const int lg   = lane >> 4;
    const int c    = tid & 127;        // epilogue column
    const int r0   = tid >> 7;         // epilogue row phase 0..3

    // wave-constant B base
    const ushort* whiW = whi + (size_t)(g * 64 + ch * 32) * 512 + lane * 8;
    const ushort* wloW = wlo + (size_t)(g * 64 + ch * 32) * 512 + lane * 8;

    // ---- K-loop: 3-term split-precision MFMA ----
    f32x4 acc[2][4] = {};   // [mi][ni]; wave tile = 32 rows x 64 cols

    #pragma unroll
    for (int kk = 0; kk < 8; ++kk) {
        bf16x8 ah[2], al[2];
        #pragma unroll
        for (int mi = 0; mi < 2; ++mi) {
            int row = mi * 16 + l15;
            int q   = kk * 4 + lg;
            int byt = row * 512 + ((q ^ (row & 7)) << 4);
            ah[mi] = *reinterpret_cast<const bf16x8*>(AhiB + byt);
            al[mi] = *reinterpret_cast<const bf16x8*>(AloB + byt);
        }
        #pragma unroll
        for (int ni = 0; ni < 4; ++ni) {
            int eoff = (ni * 8 + kk) * 512;
            bf16x8 bh = *reinterpret_cast<const bf16x8*>(whiW + eoff);
            bf16x8 bl = *reinterpret_cast<const bf16x8*>(wloW + eoff);
            #pragma unroll
            for (int mi = 0; mi < 2; ++mi)
                acc[mi][ni] = __builtin_amdgcn_mfma_f32_16x16x32_bf16(ah[mi], bh, acc[mi][ni], 0, 0, 0);
            #pragma unroll
            for (int mi = 0; mi < 2; ++mi)
                acc[mi][ni] = __builtin_amdgcn_mfma_f32_16x16x32_bf16(ah[mi], bl, acc[mi][ni], 0, 0, 0);
            #pragma unroll
            for (int mi = 0; mi < 2; ++mi)
                acc[mi][ni] = __builtin_amdgcn_mfma_f32_16x16x32_bf16(al[mi], bh, acc[mi][ni], 0, 0, 0);
        }
    }
    __syncthreads();   // bar 2: all A-LDS reads done; safe to overwrite as pre

    // ---- single-chunk epilogue: all 32 rows at once ----
    const size_t OUTS = (size_t)NROWS * 128;
    const float* cB = cprev + (size_t)row0 * 128 + c;
    const float* nB = nprev + (size_t)row0 * 128 + c;
    float* outB = out + (size_t)row0 * 128 + c;
    const float bic = bi[c], bfc = bfg[c], boc = bo[c], bzc = bz[c];

    #pragma unroll
    for (int mi = 0; mi < 2; ++mi)
        #pragma unroll
        for (int ni = 0; ni < 4; ++ni) {
            int colF = g * 128 + ch * 64 + ni * 16 + l15;
            #pragma unroll
            for (int r = 0; r < 4; ++r) {
                int rowp = mi * 16 + lg * 4 + r;   // 0..31
                pre[rowp * 512 + (colF ^ ((rowp & 4) << 2))] = acc[mi][ni][r];
            }
        }

    // JIT c/n loads: acc is dead now, regs are free; latency hides
    // under the barrier + the co-resident block's compute
    float cpv[8], npv[8];
    #pragma unroll
    for (int it = 0; it < 8; ++it) {
        int off = (r0 + it * 4) * 128;
        cpv[it] = cB[off];
        npv[it] = nB[off];
    }
    __syncthreads();   // bar 3

    #pragma unroll
    for (int it = 0; it < 8; ++it) {
        int rl = r0 + it * 4;          // 0..31
        int sw = (rl & 4) << 2;
        float pit = pre[rl * 512 + ((      c) ^ sw)] + bic;
        float pft = pre[rl * 512 + ((128 + c) ^ sw)] + bfc;
        float pot = pre[rl * 512 + ((256 + c) ^ sw)] + boc;
        float pzt = pre[rl * 512 + ((384 + c) ^ sw)] + bzc;
        float m   = fmaxf(pft, pit);
        float i_t = __expf(pit - m);
        float f_t = __builtin_amdgcn_rcpf(1.0f + __expf(-pft)) + __expf(pft - m);
        float o_t = __builtin_amdgcn_rcpf(1.0f + __expf(-pot));
        float zc  = fminf(fmaxf(pzt, -15.0f), 15.0f);
        float e2  = __expf(2.0f * zc);
        float z_t = (e2 - 1.0f) * __builtin_amdgcn_rcpf(e2 + 1.0f);
        float c_t = f_t * cpv[it] + i_t * z_t;
        float n_t = f_t * npv[it] + i_t;
        float h_t = o_t * c_t * __builtin_amdgcn_rcpf(n_t + 1e-8f);
        int off = rl * 128;
        outB[off]            = h_t;
        outB[OUTS + off]     = c_t;
        outB[2 * OUTS + off] = n_t;
    }
}

extern "C" void kernel_launch(void* const* d_in, const int* in_sizes, int n_in,
                              void* d_out, int out_size, void* d_ws, size_t ws_size,
                              hipStream_t stream) {
    const float* x  = (const float*)d_in[0];
    const float* h  = (const float*)d_in[1];
    const float* cp = (const float*)d_in[2];
    const float* np = (const float*)d_in[3];
    const float* Wi = (const float*)d_in[4];
    const float* Ui = (const float*)d_in[5];
    const float* Wf = (const float*)d_in[6];
    const float* Uf = (const float*)d_in[7];
    const float* Wo = (const float*)d_in[8];
    const float* Uo = (const float*)d_in[9];
    const float* Wz = (const float*)d_in[10];
    const float* Uz = (const float*)d_in[11];
    const float* bi = (const float*)d_in[12];
    const float* bf = (const float*)d_in[13];
    const float* bo = (const float*)d_in[14];
    const float* bz = (const float*)d_in[15];

    ushort* whi = (ushort*)d_ws;                  // 256 KB
    ushort* wlo = whi + 4 * 128 * 256;            // 256 KB

    prep_weights<<<512, 256, 0, stream>>>(Wi, Ui, Wf, Uf, Wo, Uo, Wz, Uz, whi, wlo);
    slstm_main<<<NBLKS, 512, 0, stream>>>(x, h, cp, np, bi, bf, bo, bz, whi, wlo,
                                          (float*)d_out);
}

// Round 9
// 326.794 us; speedup vs baseline: 1.5999x; 1.0170x over previous
//
#include <hip/hip_runtime.h>
#include <hip/hip_bf16.h>

typedef __attribute__((ext_vector_type(8))) short bf16x8;
typedef __attribute__((ext_vector_type(4))) float f32x4;

#define NROWS 262144
#define MBLK  32
#define NBLKS (NROWS / MBLK)   /* 8192 */

// ---------------------------------------------------------------------------
// Weight prep: B-fragment layout keyed by (wave, gate, kk):
//   elem (w, g, kk, lane, j) = Wbig[g][n = w*16 + (lane&15)]
//                                   [k = kk*32 + (lane>>4)*8 + j]
// where Wbig[g][n][k] = W_g[n][k] for k<128 else U_g[n][k-128].
// Wave w loads, per (g,kk), one coalesced 1KB chunk at
//   ((w*32 + g*8 + kk)*64 + lane)*8.
// ---------------------------------------------------------------------------
__global__ void prep_weights(
    const float* __restrict__ Wi, const float* __restrict__ Ui,
    const float* __restrict__ Wf, const float* __restrict__ Uf,
    const float* __restrict__ Wo, const float* __restrict__ Uo,
    const float* __restrict__ Wz, const float* __restrict__ Uz,
    ushort* __restrict__ hi, ushort* __restrict__ lo)
{
    int idx = blockIdx.x * 256 + threadIdx.x;   // 0..131071
    int j    = idx & 7;
    int lane = (idx >> 3) & 63;
    int kk   = (idx >> 9) & 7;
    int g    = (idx >> 12) & 3;
    int w    = (idx >> 14) & 7;
    int n = w * 16 + (lane & 15);
    int k = kk * 32 + (lane >> 4) * 8 + j;
    const float* W; const float* U;
    if (g == 0)      { W = Wi; U = Ui; }
    else if (g == 1) { W = Wf; U = Uf; }
    else if (g == 2) { W = Wo; U = Uo; }
    else             { W = Wz; U = Uz; }
    float v = (k < 128) ? W[n * 128 + k] : U[n * 128 + (k - 128)];
    __hip_bfloat16 hb = __float2bfloat16(v);
    float r = v - __bfloat162float(hb);
    __hip_bfloat16 lb = __float2bfloat16(r);
    hi[idx] = *reinterpret_cast<ushort*>(&hb);
    lo[idx] = *reinterpret_cast<ushort*>(&lb);
}

// ---------------------------------------------------------------------------
// Main fused kernel. 8192 blocks; 512 thr = 8 waves; MBLK=32 rows/block.
// Wave w owns output cols [16w,16w+16) and computes ALL FOUR gate preacts
// for them: acc[4][2] (32 regs). Gating is then fully IN-REGISTER --
// no LDS exchange, no pre buffer, ONE barrier per kernel.
// LDS = 32 KB (A-tile hi/lo only) -> 3 blocks/CU at ~85 unified regs.
// ---------------------------------------------------------------------------
__global__ __launch_bounds__(512, 4) void slstm_main(
    const float* __restrict__ x,     const float* __restrict__ hprev,
    const float* __restrict__ cprev, const float* __restrict__ nprev,
    const float* __restrict__ bi,    const float* __restrict__ bfg,
    const float* __restrict__ bo,    const float* __restrict__ bz,
    const ushort* __restrict__ whi,  const ushort* __restrict__ wlo,
    float* __restrict__ out)
{
    __shared__ ushort Ahi[32 * 256];   // 16 KB, swizzled bf16-hi of [x|h]
    __shared__ ushort Alo[32 * 256];   // 16 KB, swizzled bf16-lo
    char* AhiB = reinterpret_cast<char*>(Ahi);
    char* AloB = reinterpret_cast<char*>(Alo);

    const int tid  = threadIdx.x;
    const int row0 = blockIdx.x * MBLK;

    // ---- stage A: fp32 loads, split to bf16 hi+lo, swizzled LDS ----
    #pragma unroll
    for (int i = 0; i < 2; ++i) {
        int f4  = tid + i * 512;          // 0..1023
        int row = f4 >> 5;                // 0..31
        int c4  = f4 & 31;
        f32x4 vx = reinterpret_cast<const f32x4*>(x)[(size_t)(row0 + row) * 32 + c4];
        f32x4 vh = reinterpret_cast<const f32x4*>(hprev)[(size_t)(row0 + row) * 32 + c4];
        #pragma unroll
        for (int half = 0; half < 2; ++half) {
            f32x4 v = half ? vh : vx;
            int kbase = half * 128 + 4 * c4;
            int q   = kbase >> 3;
            int sub = (kbase & 7) * 2;
            int byt = row * 512 + ((q ^ (row & 7)) << 4) + sub;
            ushort h4[4], l4v[4];
            #pragma unroll
            for (int e = 0; e < 4; ++e) {
                float ve = v[e];
                __hip_bfloat16 hb = __float2bfloat16(ve);
                float r = ve - __bfloat162float(hb);
                __hip_bfloat16 lb = __float2bfloat16(r);
                h4[e]  = *reinterpret_cast<ushort*>(&hb);
                l4v[e] = *reinterpret_cast<ushort*>(&lb);
            }
            uint2 hp, lp;
            hp.x = (uint)h4[0] | ((uint)h4[1] << 16);
            hp.y = (uint)h4[2] | ((uint)h4[3] << 16);
            lp.x = (uint)l4v[0] | ((uint)l4v[1] << 16);
            lp.y = (uint)l4v[2] | ((uint)l4v[3] << 16);
            *reinterpret_cast<uint2*>(AhiB + byt) = hp;
            *reinterpret_cast<uint2*>(AloB + byt) = lp;
        }
    }
    __syncthreads();   // the ONLY barrier

    const int w    = tid >> 6;         // wave id = column group
    const int lane = tid & 63;
    const int l15  = lane & 15;
    const int lg   = lane >> 4;

    // wave-constant B base (this wave's 16-col slice, all gates)
    const ushort* whiW = whi + (size_t)(w * 32) * 512 + lane * 8;
    const ushort* wloW = wlo + (size_t)(w * 32) * 512 + lane * 8;

    // ---- K-loop: 3-term split-precision MFMA; acc[gate][mi] ----
    f32x4 acc[4][2] = {};

    #pragma unroll
    for (int kk = 0; kk < 8; ++kk) {
        bf16x8 ah[2], al[2];
        #pragma unroll
        for (int mi = 0; mi < 2; ++mi) {
            int row = mi * 16 + l15;
            int q   = kk * 4 + lg;
            int byt = row * 512 + ((q ^ (row & 7)) << 4);
            ah[mi] = *reinterpret_cast<const bf16x8*>(AhiB + byt);
            al[mi] = *reinterpret_cast<const bf16x8*>(AloB + byt);
        }
        #pragma unroll
        for (int g = 0; g < 4; ++g) {
            int eoff = (g * 8 + kk) * 512;
            bf16x8 bh = *reinterpret_cast<const bf16x8*>(whiW + eoff);
            bf16x8 bl = *reinterpret_cast<const bf16x8*>(wloW + eoff);
            #pragma unroll
            for (int mi = 0; mi < 2; ++mi)
                acc[g][mi] = __builtin_amdgcn_mfma_f32_16x16x32_bf16(ah[mi], bh, acc[g][mi], 0, 0, 0);
            #pragma unroll
            for (int mi = 0; mi < 2; ++mi)
                acc[g][mi] = __builtin_amdgcn_mfma_f32_16x16x32_bf16(ah[mi], bl, acc[g][mi], 0, 0, 0);
            #pragma unroll
            for (int mi = 0; mi < 2; ++mi)
                acc[g][mi] = __builtin_amdgcn_mfma_f32_16x16x32_bf16(al[mi], bh, acc[g][mi], 0, 0, 0);
        }
    }

    // ---- fully in-register epilogue ----
    // lane holds, for col c = w*16+l15, rows mi*16 + lg*4 + r (r=0..3):
    //   pit=acc[0], pft=acc[1], pot=acc[2], pzt=acc[3]
    const size_t OUTS = (size_t)NROWS * 128;
    const int c = w * 16 + l15;
    const float bic = bi[c], bfc = bfg[c], boc = bo[c], bzc = bz[c];
    const float* cB = cprev + (size_t)row0 * 128 + c;
    const float* nB = nprev + (size_t)row0 * 128 + c;
    float* outB = out + (size_t)row0 * 128 + c;

    // issue all c/n loads first (latency overlaps across the 8 gatings)
    float cpv[2][4], npv[2][4];
    #pragma unroll
    for (int mi = 0; mi < 2; ++mi)
        #pragma unroll
        for (int r = 0; r < 4; ++r) {
            int off = (mi * 16 + lg * 4 + r) * 128;
            cpv[mi][r] = cB[off];
            npv[mi][r] = nB[off];
        }

    #pragma unroll
    for (int mi = 0; mi < 2; ++mi)
        #pragma unroll
        for (int r = 0; r < 4; ++r) {
            float pit = acc[0][mi][r] + bic;
            float pft = acc[1][mi][r] + bfc;
            float pot = acc[2][mi][r] + boc;
            float pzt = acc[3][mi][r] + bzc;
            float m   = fmaxf(pft, pit);
            float i_t = __expf(pit - m);
            float f_t = __builtin_amdgcn_rcpf(1.0f + __expf(-pft)) + __expf(pft - m);
            float o_t = __builtin_amdgcn_rcpf(1.0f + __expf(-pot));
            float zc  = fminf(fmaxf(pzt, -15.0f), 15.0f);
            float e2  = __expf(2.0f * zc);
            float z_t = (e2 - 1.0f) * __builtin_amdgcn_rcpf(e2 + 1.0f);
            float c_t = f_t * cpv[mi][r] + i_t * z_t;
            float n_t = f_t * npv[mi][r] + i_t;
            float h_t = o_t * c_t * __builtin_amdgcn_rcpf(n_t + 1e-8f);
            int off = (mi * 16 + lg * 4 + r) * 128;
            outB[off]            = h_t;
            outB[OUTS + off]     = c_t;
            outB[2 * OUTS + off] = n_t;
        }
}

extern "C" void kernel_launch(void* const* d_in, const int* in_sizes, int n_in,
                              void* d_out, int out_size, void* d_ws, size_t ws_size,
                              hipStream_t stream) {
    const float* x  = (const float*)d_in[0];
    const float* h  = (const float*)d_in[1];
    const float* cp = (const float*)d_in[2];
    const float* np = (const float*)d_in[3];
    const float* Wi = (const float*)d_in[4];
    const float* Ui = (const float*)d_in[5];
    const float* Wf = (const float*)d_in[6];
    const float* Uf = (const float*)d_in[7];
    const float* Wo = (const float*)d_in[8];
    const float* Uo = (const float*)d_in[9];
    const float* Wz = (const float*)d_in[10];
    const float* Uz = (const float*)d_in[11];
    const float* bi = (const float*)d_in[12];
    const float* bf = (const float*)d_in[13];
    const float* bo = (const float*)d_in[14];
    const float* bz = (const float*)d_in[15];

    ushort* whi = (ushort*)d_ws;                  // 256 KB
    ushort* wlo = whi + 4 * 128 * 256;            // 256 KB

    prep_weights<<<512, 256, 0, stream>>>(Wi, Ui, Wf, Uf, Wo, Uo, Wz, Uz, whi, wlo);
    slstm_main<<<NBLKS, 512, 0, stream>>>(x, h, cp, np, bi, bf, bo, bz, whi, wlo,
                                          (float*)d_out);
}